// Round 5
// baseline (779.345 us; speedup 1.0000x reference)
//
#include <hip/hip_runtime.h>
#include <hip/hip_bf16.h>
#include <cstdint>

#define B_   2
#define S_   2048
#define HID_ 3072
#define H_   16
#define KV_  8
#define D_   256
#define HD_  4096   // H_*D_
#define KVD_ 2048   // KV_*D_
#define QKS_ 8192   // merged qkv row stride

constexpr float EPS_   = 1e-6f;
constexpr float SCALE_ = 0.0625f;   // 256^-0.5

typedef unsigned short u16;
typedef __attribute__((ext_vector_type(8))) short bf16x8;
typedef __attribute__((ext_vector_type(4))) float f32x4;

__device__ inline float bf2f(u16 u) { return __uint_as_float(((unsigned int)u) << 16); }
__device__ inline u16 f2bf(float f) {
  unsigned int x = __float_as_uint(f);
  x += 0x7fffu + ((x >> 16) & 1u);   // RNE
  return (u16)(x >> 16);
}

// async global->LDS, 16B per lane; lds base must be wave-uniform, data lands at base + lane*16
__device__ inline void gll16(const u16* g, u16* l) {
  __builtin_amdgcn_global_load_lds((const __attribute__((address_space(1))) unsigned int*)g,
                                   (__attribute__((address_space(3))) unsigned int*)l,
                                   16, 0, 0);
}

// ---------------- elementwise cast f32 -> bf16 (n4 = n/4) ----------------
__global__ void cast_f32_bf16(const float* __restrict__ in, u16* __restrict__ out, int n4) {
  int i = blockIdx.x * blockDim.x + threadIdx.x;
  if (i < n4) {
    float4 v = ((const float4*)in)[i];
    ushort4 o;
    o.x = f2bf(v.x); o.y = f2bf(v.y); o.z = f2bf(v.z); o.w = f2bf(v.w);
    ((ushort4*)out)[i] = o;
  }
}

// ------------- transpose+cast: in[K][N] f32 -> out[N][K] bf16 -------------
__global__ void transpose_cast(const float* __restrict__ in, u16* __restrict__ out, int K, int N) {
  __shared__ __align__(16) float tile[64][65];
  int n0 = blockIdx.x * 64, k0 = blockIdx.y * 64;
  int t = threadIdx.x;
  int rr = t >> 4, cc = (t & 15) * 4;
  for (int i = 0; i < 4; i++) {
    float4 v = *(const float4*)(&in[(size_t)(k0 + rr + 16 * i) * N + n0 + cc]);
    tile[rr + 16 * i][cc + 0] = v.x; tile[rr + 16 * i][cc + 1] = v.y;
    tile[rr + 16 * i][cc + 2] = v.z; tile[rr + 16 * i][cc + 3] = v.w;
  }
  __syncthreads();
  for (int i = 0; i < 4; i++) {
    int orow = rr + 16 * i;  // n index
    ushort4 o;
    o.x = f2bf(tile[cc + 0][orow]); o.y = f2bf(tile[cc + 1][orow]);
    o.z = f2bf(tile[cc + 2][orow]); o.w = f2bf(tile[cc + 3][orow]);
    *(ushort4*)(&out[(size_t)(n0 + orow) * K + k0 + cc]) = o;
  }
}

// ----- bf16 transpose: in (xqkv V cols, stride 8192) -> out[b][2048 n][2048 s] -----
__global__ void transpose_v(const u16* __restrict__ in, u16* __restrict__ out) {
  __shared__ __align__(16) u16 tile[64][68];
  int n0 = blockIdx.x * 64, tk0 = blockIdx.y * 64;
  int b = tk0 >> 11, s0 = tk0 & (S_ - 1);
  int t = threadIdx.x;
  int rr = t >> 4, cc = (t & 15) * 4;
  for (int i = 0; i < 4; i++) {
    ushort4 v = *(const ushort4*)(&in[(size_t)(tk0 + rr + 16 * i) * QKS_ + n0 + cc]);
    tile[rr + 16 * i][cc + 0] = v.x; tile[rr + 16 * i][cc + 1] = v.y;
    tile[rr + 16 * i][cc + 2] = v.z; tile[rr + 16 * i][cc + 3] = v.w;
  }
  __syncthreads();
  for (int i = 0; i < 4; i++) {
    int orow = rr + 16 * i;  // n index
    ushort4 o;
    o.x = tile[cc + 0][orow]; o.y = tile[cc + 1][orow];
    o.z = tile[cc + 2][orow]; o.w = tile[cc + 3][orow];
    *(ushort4*)(&out[((size_t)b << 22) + (size_t)(n0 + orow) * S_ + s0 + cc]) = o;
  }
}

// ===== 256x256 8-wave 4-phase GEMM: C[M][N] = A[M][K] * Bt[N][K]^T =====
// v2 schedule: software-pipelined fragment reads with COUNTED lgkmcnt (reads
// for phase p+1 issued during phase p), no sched_barrier. Staging WAR-safe:
// each subtile staged >=1 barrier after the counted-lgkm that retired its
// last read (A0/B01 retired ph1 -> staged ph2; B23 ph2 -> ph3; A1 ph3 -> ph4).
// stages during K-tile t target t+2; vmcnt(8) gate per tile (vmcnt(0) when
// no stage issued this tile).
template <bool OUTF32>
__global__ __launch_bounds__(512, 2) void gemm256(const u16* __restrict__ A,
                                                  const u16* __restrict__ Bt,
                                                  void* __restrict__ Cv, int M, int N, int K) {
  __shared__ __align__(16) u16 As[2][16384];
  __shared__ __align__(16) u16 Bs[2][16384];
  int t = threadIdx.x, lane = t & 63, wave = t >> 6;
  int quad = lane >> 4, l16 = lane & 15;
  int wm = wave >> 2, wn = wave & 3;

  // XCD-chunked bid swizzle (requires nwg % 8 == 0; 512 and 192 both qualify)
  int nwg = gridDim.x * gridDim.y;
  int bid = blockIdx.y * gridDim.x + blockIdx.x;
  int sbid = (bid & 7) * (nwg >> 3) + (bid >> 3);
  int bn = (sbid % gridDim.x) * 256;
  int bm = (sbid / gridDim.x) * 256;

  // staging: one gll16 fills one 16x32 subtile (1KB); lane l -> row l>>2,
  // phys slot l&3 holding logical slot (l&3)^((l>>3)&3)
  int srow = lane >> 2;
  int scol8 = ((lane & 3) ^ ((lane >> 3) & 3)) * 8;
  const u16* ap = A + (size_t)(bm + srow) * K + scol8;
  const u16* bp = Bt + (size_t)(bn + srow) * K + scol8;
  int ha1 = (wave & 3) + ((wave >> 2) << 3);   // {0,1,2,3,8,9,10,11}
  int hb1 = (wave & 1) + ((wave >> 1) << 2);   // {0,1,4,5,8,9,12,13}

  auto stA = [&](int sr, int sc, int k0, int bufi) {
    gll16(ap + (size_t)(sr * 16) * K + k0 + sc * 32, &As[bufi][(sr * 2 + sc) * 512]);
  };
  auto stB = [&](int sr, int sc, int k0, int bufi) {
    gll16(bp + (size_t)(sr * 16) * K + k0 + sc * 32, &Bs[bufi][(sr * 2 + sc) * 512]);
  };

  // frag read offset within a subtile (uniform banks: slot = quad ^ ((l16>>1)&3))
  int rsw = l16 * 32 + ((quad ^ ((l16 >> 1) & 3)) * 8);
#define LDA8(i, ks) (*(const bf16x8*)(&As[cur][((wm * 8 + (i)) * 2 + (ks)) * 512 + rsw]))
#define LDB8(j, ks) (*(const bf16x8*)(&Bs[cur][((wn * 4 + (j)) * 2 + (ks)) * 512 + rsw]))

  f32x4 acc[8][4] = {};
  int NT = K >> 6;

  // prologue: stage K-tiles 0,1 fully (8 gll16 each per wave)
#pragma unroll
  for (int h = 0; h < 2; h++) {
    int k0 = h * 64;
    stA(ha1, 0, k0, h); stA(ha1, 1, k0, h);
    stA(ha1 + 4, 0, k0, h); stA(ha1 + 4, 1, k0, h);
    stB(hb1, 0, k0, h); stB(hb1, 1, k0, h);
    stB(hb1 + 2, 0, k0, h); stB(hb1 + 2, 1, k0, h);
  }
  asm volatile("s_waitcnt vmcnt(8)" ::: "memory");   // tile 0 landed
  __builtin_amdgcn_s_barrier();
  asm volatile("" ::: "memory");

#pragma unroll 1
  for (int kt = 0; kt < NT; kt++) {
    int cur = kt & 1;
    int kp = (kt + 2) * 64;
    bool pre = (kt + 2) < NT;
    bf16x8 a0[4][2], a1[4][2], b[4][2];
    // ---- ph1: read A0(8)+B01(4)+B23(4); lgkm(4) [B23 may fly]; MFMA (m0,n01) ----
#pragma unroll
    for (int i = 0; i < 4; i++) { a0[i][0] = LDA8(i, 0); a0[i][1] = LDA8(i, 1); }
#pragma unroll
    for (int j = 0; j < 2; j++) { b[j][0] = LDB8(j, 0); b[j][1] = LDB8(j, 1); }
#pragma unroll
    for (int j = 2; j < 4; j++) { b[j][0] = LDB8(j, 0); b[j][1] = LDB8(j, 1); }
    __builtin_amdgcn_s_barrier();
    asm volatile("s_waitcnt lgkmcnt(4)" ::: "memory");
    __builtin_amdgcn_s_setprio(1);
#pragma unroll
    for (int i = 0; i < 4; i++)
#pragma unroll
      for (int j = 0; j < 2; j++) {
        acc[i][j] = __builtin_amdgcn_mfma_f32_16x16x32_bf16(a0[i][0], b[j][0], acc[i][j], 0, 0, 0);
        acc[i][j] = __builtin_amdgcn_mfma_f32_16x16x32_bf16(a0[i][1], b[j][1], acc[i][j], 0, 0, 0);
      }
    __builtin_amdgcn_s_setprio(0);
    __builtin_amdgcn_s_barrier();
    // ---- ph2: read A1(8); stage ha1+hb1(t+2); lgkm(8) [A1 may fly]; MFMA (m0,n23) ----
#pragma unroll
    for (int i = 0; i < 4; i++) { a1[i][0] = LDA8(i + 4, 0); a1[i][1] = LDA8(i + 4, 1); }
    if (pre) { stA(ha1, 0, kp, cur); stA(ha1, 1, kp, cur);
               stB(hb1, 0, kp, cur); stB(hb1, 1, kp, cur); }
    __builtin_amdgcn_s_barrier();
    asm volatile("s_waitcnt lgkmcnt(8)" ::: "memory");
    __builtin_amdgcn_s_setprio(1);
#pragma unroll
    for (int i = 0; i < 4; i++)
#pragma unroll
      for (int j = 2; j < 4; j++) {
        acc[i][j] = __builtin_amdgcn_mfma_f32_16x16x32_bf16(a0[i][0], b[j][0], acc[i][j], 0, 0, 0);
        acc[i][j] = __builtin_amdgcn_mfma_f32_16x16x32_bf16(a0[i][1], b[j][1], acc[i][j], 0, 0, 0);
      }
    __builtin_amdgcn_s_setprio(0);
    __builtin_amdgcn_s_barrier();
    // ---- ph3: stage hb1+2(t+2); lgkm(0) [A1 done]; MFMA (m1,n23) ----
    if (pre) { stB(hb1 + 2, 0, kp, cur); stB(hb1 + 2, 1, kp, cur); }
    __builtin_amdgcn_s_barrier();
    asm volatile("s_waitcnt lgkmcnt(0)" ::: "memory");
    __builtin_amdgcn_s_setprio(1);
#pragma unroll
    for (int i = 0; i < 4; i++)
#pragma unroll
      for (int j = 2; j < 4; j++) {
        acc[i + 4][j] = __builtin_amdgcn_mfma_f32_16x16x32_bf16(a1[i][0], b[j][0], acc[i + 4][j], 0, 0, 0);
        acc[i + 4][j] = __builtin_amdgcn_mfma_f32_16x16x32_bf16(a1[i][1], b[j][1], acc[i + 4][j], 0, 0, 0);
      }
    __builtin_amdgcn_s_setprio(0);
    __builtin_amdgcn_s_barrier();
    // ---- ph4: stage ha1+4(t+2); MFMA (m1,n01) [all regs live]; vmcnt gate ----
    if (pre) { stA(ha1 + 4, 0, kp, cur); stA(ha1 + 4, 1, kp, cur); }
    __builtin_amdgcn_s_setprio(1);
#pragma unroll
    for (int i = 0; i < 4; i++)
#pragma unroll
      for (int j = 0; j < 2; j++) {
        acc[i + 4][j] = __builtin_amdgcn_mfma_f32_16x16x32_bf16(a1[i][0], b[j][0], acc[i + 4][j], 0, 0, 0);
        acc[i + 4][j] = __builtin_amdgcn_mfma_f32_16x16x32_bf16(a1[i][1], b[j][1], acc[i + 4][j], 0, 0, 0);
      }
    __builtin_amdgcn_s_setprio(0);
    if (pre) asm volatile("s_waitcnt vmcnt(8)" ::: "memory");  // tile t+1 fully landed
    else     asm volatile("s_waitcnt vmcnt(0)" ::: "memory");
    __builtin_amdgcn_s_barrier();
    asm volatile("" ::: "memory");
  }

  // epilogue
#pragma unroll
  for (int i = 0; i < 8; i++)
#pragma unroll
    for (int j = 0; j < 4; j++)
#pragma unroll
      for (int r = 0; r < 4; r++) {
        int row = bm + wm * 128 + i * 16 + quad * 4 + r;
        int col = bn + wn * 64 + j * 16 + l16;
        float v = acc[i][j][r];
        if (OUTF32) ((float*)Cv)[(size_t)row * N + col] = v;
        else ((u16*)Cv)[(size_t)row * N + col] = f2bf(v);
      }
#undef LDA8
#undef LDB8
}

// ----- fused RMSNorm + RoPE, in place on bf16 [token][stride]; 1 wave/head -----
__global__ void rmsnorm_rope(u16* __restrict__ x, const float* __restrict__ w,
                             const float* __restrict__ fc, const float* __restrict__ fsn,
                             int nh, int stride, float outscale) {
  int token = blockIdx.x;
  int head = blockIdx.y * 4 + (threadIdx.x >> 6);
  if (head >= nh) return;
  int lane = threadIdx.x & 63;
  int s = token & (S_ - 1);
  u16* p = x + (size_t)token * stride + head * D_;
  float v0 = bf2f(p[lane]);
  float v1 = bf2f(p[lane + 64]);
  float v2 = bf2f(p[lane + 128]);
  float v3 = bf2f(p[lane + 192]);
  float ss = v0 * v0 + v1 * v1 + v2 * v2 + v3 * v3;
  for (int off = 32; off; off >>= 1) ss += __shfl_xor(ss, off, 64);
  float rs = rsqrtf(ss * (1.0f / D_) + EPS_);
  float n0 = v0 * rs * (1.0f + w[lane]);
  float n1 = v1 * rs * (1.0f + w[lane + 64]);
  float n2 = v2 * rs * (1.0f + w[lane + 128]);
  float n3 = v3 * rs * (1.0f + w[lane + 192]);
  float c0 = fc[s * 128 + lane], s0 = fsn[s * 128 + lane];
  float c1 = fc[s * 128 + lane + 64], s1 = fsn[s * 128 + lane + 64];
  p[lane]       = f2bf((n0 * c0 - n2 * s0) * outscale);
  p[lane + 128] = f2bf((n0 * s0 + n2 * c0) * outscale);
  p[lane + 64]  = f2bf((n1 * c1 - n3 * s1) * outscale);
  p[lane + 192] = f2bf((n1 * s1 + n3 * c1) * outscale);
}

// ---------------- flash attention, causal, GQA rep=2, D=256 ----------------
// v4 + merged-qkv strides: Q/K rows have stride 8192.
__global__ __launch_bounds__(256, 3) void flash_attn(const u16* __restrict__ Q,
                                                     const u16* __restrict__ Kb,
                                                     const u16* __restrict__ Vt,
                                                     u16* __restrict__ O) {
  __shared__ __align__(16) u16 Ks[2][8 * 1024];   // [buf][chunk c][key 0..31][slot-swz 32 d]
  __shared__ __align__(16) u16 Vs[8 * 1024];      // [d 0..255][slot-swz 32 k]
  int t = threadIdx.x, lane = t & 63, wave = t >> 6;
  int quad = lane >> 4, l16 = lane & 15;
  int h = blockIdx.y, b = blockIdx.z;
  int kvh = h >> 1;

  int swz = ((lane & 3) ^ ((lane >> 2) & 3)) * 8;        // staging-side d/k offset
  int rswz = (quad ^ (l16 & 3)) * 8;                     // read-side slot offset
  const u16* kst = Kb + (size_t)(b * S_ + (lane >> 2)) * QKS_ + kvh * D_ + wave * 64 + swz;
  const u16* vst = Vt + ((size_t)b << 22) + (size_t)(kvh * D_ + wave * 64 + (lane >> 2)) * S_ + swz;

  auto stageK = [&](int kt, int bufi) {
    u16* kdst = &Ks[bufi][wave * 2048];
    const u16* ksrc = kst + (size_t)(kt * 32) * QKS_;
#pragma unroll
    for (int c2 = 0; c2 < 2; c2++)
#pragma unroll
      for (int r = 0; r < 2; r++)
        gll16(ksrc + (size_t)(r * 16) * QKS_ + c2 * 32, kdst + c2 * 1024 + r * 512);
  };  // 4 gll16
  auto stageV = [&](int kt) {
    u16* vdst = &Vs[wave * 2048];
#pragma unroll
    for (int c = 0; c < 4; c++)
      gll16(vst + (size_t)(c * 16) * S_ + kt * 32, vdst + c * 512);
  };  // 4 gll16

#pragma unroll 1
  for (int half = 0; half < 2; half++) {
    // big q-tile first, then the paired small one: iters (64-2bx) + (2bx+2) = 66
    int qb = (half == 0) ? (31 - (int)blockIdx.x) * 64 : (int)blockIdx.x * 64;
    int qw = qb + wave * 16;

    bf16x8 qf[8];
    const u16* qp = Q + ((size_t)(b * S_) + qw + l16) * QKS_ + h * D_;
#pragma unroll
    for (int c = 0; c < 8; c++) qf[c] = *(const bf16x8*)(qp + c * 32 + quad * 8);

    f32x4 o_acc[16] = {};
    float m_s = -3e38f, l_s = 0.f;    // per-lane softmax state for row q = qw + l16

    int nkt = (qb + 64) >> 5;
    stageK(0, 0);
    stageV(0);
#pragma unroll 1
    for (int kt = 0; kt < nkt; kt++) {
      int cur = kt & 1;
      asm volatile("s_waitcnt vmcnt(4)" ::: "memory");
      __builtin_amdgcn_s_barrier();
      asm volatile("" ::: "memory");
      if (kt + 1 < nkt) stageK(kt + 1, cur ^ 1);

      // ---- QK (swapped): sc[key][q], q = l16 ----
      f32x4 sc0 = {}, sc1 = {};
#pragma unroll
      for (int c = 0; c < 8; c++) {
        bf16x8 k0 = *(const bf16x8*)(&Ks[cur][c * 1024 + l16 * 32 + rswz]);
        bf16x8 k1 = *(const bf16x8*)(&Ks[cur][c * 1024 + (l16 + 16) * 32 + rswz]);
        sc0 = __builtin_amdgcn_mfma_f32_16x16x32_bf16(k0, qf[c], sc0, 0, 0, 0);
        sc1 = __builtin_amdgcn_mfma_f32_16x16x32_bf16(k1, qf[c], sc1, 0, 0, 0);
      }

      // ---- lane-local online softmax (row q = qw + l16) ----
      int qg = qw + l16;
      int kbase = kt * 32 + quad * 4;
      float p0[4], p1[4];
      float mx = -1e30f;
#pragma unroll
      for (int r = 0; r < 4; r++) {
        p0[r] = (kbase + r <= qg) ? sc0[r] : -1e30f;
        p1[r] = (kbase + 16 + r <= qg) ? sc1[r] : -1e30f;
        mx = fmaxf(mx, fmaxf(p0[r], p1[r]));
      }
      mx = fmaxf(mx, __shfl_xor(mx, 16));
      mx = fmaxf(mx, __shfl_xor(mx, 32));
      float mn = fmaxf(m_s, mx);
      bool chg = mn > m_s;
      float rsum = 0.f;
#pragma unroll
      for (int r = 0; r < 4; r++) {
        p0[r] = __expf(p0[r] - mn);
        p1[r] = __expf(p1[r] - mn);
        rsum += p0[r] + p1[r];
      }
      if (__any((int)chg)) {
        float alpha = __expf(m_s - mn);
        float ar[4];
#pragma unroll
        for (int r = 0; r < 4; r++) ar[r] = __shfl(alpha, quad * 20 + r);
#pragma unroll
        for (int nt = 0; nt < 16; nt++)
#pragma unroll
          for (int r = 0; r < 4; r++) o_acc[nt][r] *= ar[r];
        l_s *= alpha;
      }
      m_s = mn;
      rsum += __shfl_xor(rsum, 16);
      rsum += __shfl_xor(rsum, 32);
      l_s += rsum;

      // ---- P: C-layout -> A-frag fully in-register (2-stage butterfly) ----
      unsigned int w_[4], x_[4], gl[4], gh[4], sn[4], rc[4];
      w_[0] = (unsigned)f2bf(p0[0]) | ((unsigned)f2bf(p0[1]) << 16);
      w_[1] = (unsigned)f2bf(p0[2]) | ((unsigned)f2bf(p0[3]) << 16);
      w_[2] = (unsigned)f2bf(p1[0]) | ((unsigned)f2bf(p1[1]) << 16);
      w_[3] = (unsigned)f2bf(p1[2]) | ((unsigned)f2bf(p1[3]) << 16);
#pragma unroll
      for (int i = 0; i < 4; i++) x_[i] = (unsigned)__shfl_xor((int)w_[i], 16);
      bool odd = (quad & 1) != 0;
      gl[0] = odd ? x_[0] : w_[0]; gl[1] = odd ? x_[1] : w_[1];
      gl[2] = odd ? w_[0] : x_[0]; gl[3] = odd ? w_[1] : x_[1];
      gh[0] = odd ? x_[2] : w_[2]; gh[1] = odd ? x_[3] : w_[3];
      gh[2] = odd ? w_[2] : x_[2]; gh[3] = odd ? w_[3] : x_[3];
#pragma unroll
      for (int i = 0; i < 4; i++) sn[i] = odd ? gl[i] : gh[i];
#pragma unroll
      for (int i = 0; i < 4; i++) rc[i] = (unsigned)__shfl_xor((int)sn[i], 32);
      union { unsigned int u[4]; bf16x8 v; } pfc;
#pragma unroll
      for (int i = 0; i < 4; i++)
        pfc.u[i] = (quad == 0) ? gl[i] : (quad == 3) ? gh[i] : rc[i];
      bf16x8 pf = pfc.v;

      if (kt + 1 < nkt) asm volatile("s_waitcnt vmcnt(4)" ::: "memory");
      else              asm volatile("s_waitcnt vmcnt(0)" ::: "memory");
      __builtin_amdgcn_s_barrier();
      asm volatile("" ::: "memory");

      // ---- PV ----
#pragma unroll
      for (int nt = 0; nt < 16; nt++) {
        bf16x8 vf = *(const bf16x8*)(&Vs[(nt * 16 + l16) * 32 + rswz]);
        o_acc[nt] = __builtin_amdgcn_mfma_f32_16x16x32_bf16(pf, vf, o_acc[nt], 0, 0, 0);
      }

      asm volatile("s_waitcnt lgkmcnt(0)" ::: "memory");
      __builtin_amdgcn_s_barrier();
      asm volatile("" ::: "memory");
      if (kt + 1 < nkt) stageV(kt + 1);
    }

    float invl = 1.0f / l_s;
    float inv_r[4];
#pragma unroll
    for (int r = 0; r < 4; r++) inv_r[r] = __shfl(invl, quad * 20 + r);
    for (int r = 0; r < 4; r++) {
      int qg2 = qw + quad * 4 + r;
      u16* op = O + ((size_t)(b * S_) + qg2) * HD_ + h * D_;
      for (int nt = 0; nt < 16; nt++) op[nt * 16 + l16] = f2bf(o_acc[nt][r] * inv_r[r]);
    }
  }
}

extern "C" void kernel_launch(void* const* d_in, const int* in_sizes, int n_in,
                              void* d_out, int out_size, void* d_ws, size_t ws_size,
                              hipStream_t stream) {
  const float* hs  = (const float*)d_in[0];
  const float* fc  = (const float*)d_in[1];
  const float* fsn = (const float*)d_in[2];
  // d_in[3] = mask: causal, replicated analytically
  const float* qw  = (const float*)d_in[4];
  const float* kw  = (const float*)d_in[5];
  const float* vw  = (const float*)d_in[6];
  const float* ow  = (const float*)d_in[7];
  const float* qnw = (const float*)d_in[8];
  const float* knw = (const float*)d_in[9];

  char* ws = (char*)d_ws;
  // layout (bytes):
  u16* x_bf   = (u16*)(ws + 0);          // 4096*3072*2 = 25165824 (dead after QKV GEMM)
  u16* vt     = (u16*)(ws + 0);          // 2*2048*2048*2 = 16777216 (overlays dead x_bf)
  u16* wqkv_t = (u16*)(ws + 25165824);   // [8192][3072] = 50331648 (q|k|v transposed, contiguous)
  u16* kw_t   = (u16*)(ws + 50331648);   // = wqkv_t + 4096 rows
  u16* vw_t   = (u16*)(ws + 62914560);   // = wqkv_t + 6144 rows
  u16* ow_t   = (u16*)(ws + 75497472);   // [3072][4096] = 25165824
  u16* xqkv   = (u16*)(ws + 100663296);  // [4096][8192] = 67108864 -> end 167772160
  u16* attn   = (u16*)(ws + 25165824);   // overlays dead wqkv_t after QKV GEMM (33.5MB <= 50.3MB)

  cast_f32_bf16<<<12288, 256, 0, stream>>>(hs, x_bf, 4096 * 3072 / 4);
  transpose_cast<<<dim3(64, 48), 256, 0, stream>>>(qw, wqkv_t, 3072, 4096);
  transpose_cast<<<dim3(32, 48), 256, 0, stream>>>(kw, kw_t, 3072, 2048);
  transpose_cast<<<dim3(32, 48), 256, 0, stream>>>(vw, vw_t, 3072, 2048);
  transpose_cast<<<dim3(48, 64), 256, 0, stream>>>(ow, ow_t, 4096, 3072);

  // merged QKV projection: [4096][3072] x [8192][3072]^T -> [4096][8192]
  gemm256<false><<<dim3(32, 16), 512, 0, stream>>>(x_bf, wqkv_t, xqkv, 4096, 8192, 3072);

  rmsnorm_rope<<<dim3(4096, 4), 256, 0, stream>>>(xqkv, qnw, fc, fsn, 16, QKS_, SCALE_);
  rmsnorm_rope<<<dim3(4096, 2), 256, 0, stream>>>(xqkv + 4096, knw, fc, fsn, 8, QKS_, 1.0f);

  transpose_v<<<dim3(32, 64), 256, 0, stream>>>(xqkv + 6144, vt);

  flash_attn<<<dim3(16, 16, 2), 256, 0, stream>>>(xqkv, xqkv + 4096, vt, attn);

  gemm256<true><<<dim3(12, 16), 512, 0, stream>>>(attn, ow_t, (float*)d_out, 4096, 3072, 4096);
}

// Round 6
// 758.080 us; speedup vs baseline: 1.0281x; 1.0281x over previous
//
#include <hip/hip_runtime.h>
#include <hip/hip_bf16.h>
#include <cstdint>

#define B_   2
#define S_   2048
#define HID_ 3072
#define H_   16
#define KV_  8
#define D_   256
#define HD_  4096   // H_*D_
#define KVD_ 2048   // KV_*D_
#define QKS_ 8192   // merged qkv row stride

constexpr float EPS_   = 1e-6f;
constexpr float SCALE_ = 0.0625f;   // 256^-0.5

typedef unsigned short u16;
typedef __attribute__((ext_vector_type(8))) short bf16x8;
typedef __attribute__((ext_vector_type(4))) float f32x4;

__device__ inline float bf2f(u16 u) { return __uint_as_float(((unsigned int)u) << 16); }
__device__ inline u16 f2bf(float f) {
  unsigned int x = __float_as_uint(f);
  x += 0x7fffu + ((x >> 16) & 1u);   // RNE
  return (u16)(x >> 16);
}

// async global->LDS, 16B per lane; lds base must be wave-uniform, data lands at base + lane*16
__device__ inline void gll16(const u16* g, u16* l) {
  __builtin_amdgcn_global_load_lds((const __attribute__((address_space(1))) unsigned int*)g,
                                   (__attribute__((address_space(3))) unsigned int*)l,
                                   16, 0, 0);
}

// ---------------- elementwise cast f32 -> bf16 (n4 = n/4) ----------------
__global__ void cast_f32_bf16(const float* __restrict__ in, u16* __restrict__ out, int n4) {
  int i = blockIdx.x * blockDim.x + threadIdx.x;
  if (i < n4) {
    float4 v = ((const float4*)in)[i];
    ushort4 o;
    o.x = f2bf(v.x); o.y = f2bf(v.y); o.z = f2bf(v.z); o.w = f2bf(v.w);
    ((ushort4*)out)[i] = o;
  }
}

// ------------- transpose+cast: in[K][N] f32 -> out[N][K] bf16 -------------
__global__ void transpose_cast(const float* __restrict__ in, u16* __restrict__ out, int K, int N) {
  __shared__ __align__(16) float tile[64][65];
  int n0 = blockIdx.x * 64, k0 = blockIdx.y * 64;
  int t = threadIdx.x;
  int rr = t >> 4, cc = (t & 15) * 4;
  for (int i = 0; i < 4; i++) {
    float4 v = *(const float4*)(&in[(size_t)(k0 + rr + 16 * i) * N + n0 + cc]);
    tile[rr + 16 * i][cc + 0] = v.x; tile[rr + 16 * i][cc + 1] = v.y;
    tile[rr + 16 * i][cc + 2] = v.z; tile[rr + 16 * i][cc + 3] = v.w;
  }
  __syncthreads();
  for (int i = 0; i < 4; i++) {
    int orow = rr + 16 * i;  // n index
    ushort4 o;
    o.x = f2bf(tile[cc + 0][orow]); o.y = f2bf(tile[cc + 1][orow]);
    o.z = f2bf(tile[cc + 2][orow]); o.w = f2bf(tile[cc + 3][orow]);
    *(ushort4*)(&out[(size_t)(n0 + orow) * K + k0 + cc]) = o;
  }
}

// ----- bf16 transpose: in (xqkv V cols, stride 8192) -> out[b][2048 n][2048 s] -----
__global__ void transpose_v(const u16* __restrict__ in, u16* __restrict__ out) {
  __shared__ __align__(16) u16 tile[64][68];
  int n0 = blockIdx.x * 64, tk0 = blockIdx.y * 64;
  int b = tk0 >> 11, s0 = tk0 & (S_ - 1);
  int t = threadIdx.x;
  int rr = t >> 4, cc = (t & 15) * 4;
  for (int i = 0; i < 4; i++) {
    ushort4 v = *(const ushort4*)(&in[(size_t)(tk0 + rr + 16 * i) * QKS_ + n0 + cc]);
    tile[rr + 16 * i][cc + 0] = v.x; tile[rr + 16 * i][cc + 1] = v.y;
    tile[rr + 16 * i][cc + 2] = v.z; tile[rr + 16 * i][cc + 3] = v.w;
  }
  __syncthreads();
  for (int i = 0; i < 4; i++) {
    int orow = rr + 16 * i;  // n index
    ushort4 o;
    o.x = tile[cc + 0][orow]; o.y = tile[cc + 1][orow];
    o.z = tile[cc + 2][orow]; o.w = tile[cc + 3][orow];
    *(ushort4*)(&out[((size_t)b << 22) + (size_t)(n0 + orow) * S_ + s0 + cc]) = o;
  }
}

// ===== 256x256 8-wave GEMM, cross-tile-pipelined reads: C = A * Bt^T =====
// v3 schedule: ds_reads run exactly ONE quadrant ahead all the way around the
// K-loop (ph1: a1, ph2: b23, ph3: next-tile b01', ph4: next-tile a0'), so the
// LDS pipe grinds during every MFMA cluster including across tile boundaries.
// Quadrant order Q1=m0n01 Q2=m1n01 Q3=m0n23 Q4=m1n23 makes operand lifetimes
// permit this with zero extra registers. Counted lgkm(8/4/4/-); one collective
// vmcnt(3)+barrier mid-tile gates next-buffer reads; 3 barriers/tile.
// Staging WAR classes: a0/b01-region staged ph2+ (reads retired ph1-lgkm),
// a1-region ph3+ (ph2-lgkm), b23-region ph4+ (ph3-lgkm); stages during tile t
// target t+2 (same buffer parity).
template <bool OUTF32>
__global__ __launch_bounds__(512, 2) void gemm256(const u16* __restrict__ A,
                                                  const u16* __restrict__ Bt,
                                                  void* __restrict__ Cv, int M, int N, int K) {
  __shared__ __align__(16) u16 As[2][16384];
  __shared__ __align__(16) u16 Bs[2][16384];
  int t = threadIdx.x, lane = t & 63, wave = t >> 6;
  int quad = lane >> 4, l16 = lane & 15;
  int wm = wave >> 2, wn = wave & 3;

  // XCD-chunked bid swizzle (requires nwg % 8 == 0; 512 and 192 both qualify)
  int nwg = gridDim.x * gridDim.y;
  int bid = blockIdx.y * gridDim.x + blockIdx.x;
  int sbid = (bid & 7) * (nwg >> 3) + (bid >> 3);
  int bn = (sbid % gridDim.x) * 256;
  int bm = (sbid / gridDim.x) * 256;

  // staging: one gll16 fills one 16x32 subtile (1KB); lane l -> row l>>2,
  // phys slot l&3 holding logical slot (l&3)^((l>>3)&3)
  int srow = lane >> 2;
  int scol8 = ((lane & 3) ^ ((lane >> 3) & 3)) * 8;
  const u16* ap = A + (size_t)(bm + srow) * K + scol8;
  const u16* bp = Bt + (size_t)(bn + srow) * K + scol8;
  // per-wave stage set: one subtile pair in each WAR class
  int nr = (wave & 1) + ((wave >> 1) << 2);   // B b01-class row; +2 = b23-class

  auto stA = [&](int sr, int sc, int k0, int bufi) {
    gll16(ap + (size_t)(sr * 16) * K + k0 + sc * 32, &As[bufi][(sr * 2 + sc) * 512]);
  };
  auto stB = [&](int sr, int sc, int k0, int bufi) {
    gll16(bp + (size_t)(sr * 16) * K + k0 + sc * 32, &Bs[bufi][(sr * 2 + sc) * 512]);
  };

  // frag read offset within a subtile (uniform banks: slot = quad ^ ((l16>>1)&3))
  int rsw = l16 * 32 + ((quad ^ ((l16 >> 1) & 3)) * 8);
  auto LDA = [&](int bufi, int i, int ks) {
    return *(const bf16x8*)(&As[bufi][((wm * 8 + i) * 2 + ks) * 512 + rsw]);
  };
  auto LDB = [&](int bufi, int j, int ks) {
    return *(const bf16x8*)(&Bs[bufi][((wn * 4 + j) * 2 + ks) * 512 + rsw]);
  };

  f32x4 acc[8][4] = {};
  int NT = K >> 6;

  // prologue: stage K-tiles 0,1 fully (8 gll16 each per wave)
#pragma unroll
  for (int h = 0; h < 2; h++) {
    int k0 = h * 64;
    stA(wave, 0, k0, h); stA(wave, 1, k0, h);
    stA(wave + 8, 0, k0, h); stA(wave + 8, 1, k0, h);
    stB(nr, 0, k0, h); stB(nr, 1, k0, h);
    stB(nr + 2, 0, k0, h); stB(nr + 2, 1, k0, h);
  }
  asm volatile("s_waitcnt vmcnt(8)" ::: "memory");   // tile 0 landed
  __builtin_amdgcn_s_barrier();
  asm volatile("" ::: "memory");

  // pre-read tile 0's Q1 operands (b01 first, then a0 — oldest in lgkm queue)
  bf16x8 A0[4][2], B01[2][2];
#pragma unroll
  for (int j = 0; j < 2; j++) { B01[j][0] = LDB(0, j, 0); B01[j][1] = LDB(0, j, 1); }
#pragma unroll
  for (int i = 0; i < 4; i++) { A0[i][0] = LDA(0, i, 0); A0[i][1] = LDA(0, i, 1); }

#pragma unroll 1
  for (int kt = 0; kt < NT; kt++) {
    int cur = kt & 1, nxt = cur ^ 1;
    int kp = (kt + 2) * 64;
    bool rd_next = (kt + 1) < NT;
    bool pre2 = (kt + 2) < NT;
    bf16x8 A1[4][2], B23[2][2];

    // ---- ph1: read a1 (8, for Q2); MFMA Q1 = m0 x n01 ----
#pragma unroll
    for (int i = 0; i < 4; i++) { A1[i][0] = LDA(cur, i + 4, 0); A1[i][1] = LDA(cur, i + 4, 1); }
    asm volatile("s_waitcnt lgkmcnt(8)" ::: "memory");   // a0/b01 done, a1 in flight
    __builtin_amdgcn_s_setprio(1);
#pragma unroll
    for (int i = 0; i < 4; i++)
#pragma unroll
      for (int j = 0; j < 2; j++) {
        acc[i][j] = __builtin_amdgcn_mfma_f32_16x16x32_bf16(A0[i][0], B01[j][0], acc[i][j], 0, 0, 0);
        acc[i][j] = __builtin_amdgcn_mfma_f32_16x16x32_bf16(A0[i][1], B01[j][1], acc[i][j], 0, 0, 0);
      }
    __builtin_amdgcn_s_setprio(0);
    __builtin_amdgcn_s_barrier();                        // enables a0/b01-region stages
    asm volatile("" ::: "memory");

    // ---- ph2: read b23 (4, for Q3); stage a0-region + b01 half; MFMA Q2 = m1 x n01 ----
#pragma unroll
    for (int j = 0; j < 2; j++) { B23[j][0] = LDB(cur, j + 2, 0); B23[j][1] = LDB(cur, j + 2, 1); }
    if (pre2) { stA(wave, 0, kp, cur); stA(wave, 1, kp, cur); stB(nr, 0, kp, cur); }
    asm volatile("s_waitcnt lgkmcnt(4)" ::: "memory");   // a1 done, b23 in flight
    __builtin_amdgcn_s_setprio(1);
#pragma unroll
    for (int i = 0; i < 4; i++)
#pragma unroll
      for (int j = 0; j < 2; j++) {
        acc[i + 4][j] = __builtin_amdgcn_mfma_f32_16x16x32_bf16(A1[i][0], B01[j][0], acc[i + 4][j], 0, 0, 0);
        acc[i + 4][j] = __builtin_amdgcn_mfma_f32_16x16x32_bf16(A1[i][1], B01[j][1], acc[i + 4][j], 0, 0, 0);
      }
    __builtin_amdgcn_s_setprio(0);
    // collective gate: tile t+1's 8 stages (issued during t-1) all landed
    if (pre2) asm volatile("s_waitcnt vmcnt(3)" ::: "memory");
    else      asm volatile("s_waitcnt vmcnt(0)" ::: "memory");
    __builtin_amdgcn_s_barrier();
    asm volatile("" ::: "memory");

    // ---- ph3: read next-tile b01' (4); stage b01 half + a1-region; MFMA Q3 = m0 x n23 ----
    if (rd_next) {
#pragma unroll
      for (int j = 0; j < 2; j++) { B01[j][0] = LDB(nxt, j, 0); B01[j][1] = LDB(nxt, j, 1); }
    }
    if (pre2) { stB(nr, 1, kp, cur); stA(wave + 8, 0, kp, cur); stA(wave + 8, 1, kp, cur); }
    if (rd_next) asm volatile("s_waitcnt lgkmcnt(4)" ::: "memory");  // b23 done
    else         asm volatile("s_waitcnt lgkmcnt(0)" ::: "memory");
    __builtin_amdgcn_s_setprio(1);
#pragma unroll
    for (int i = 0; i < 4; i++)
#pragma unroll
      for (int j = 0; j < 2; j++) {
        acc[i][j + 2] = __builtin_amdgcn_mfma_f32_16x16x32_bf16(A0[i][0], B23[j][0], acc[i][j + 2], 0, 0, 0);
        acc[i][j + 2] = __builtin_amdgcn_mfma_f32_16x16x32_bf16(A0[i][1], B23[j][1], acc[i][j + 2], 0, 0, 0);
      }
    __builtin_amdgcn_s_setprio(0);
    __builtin_amdgcn_s_barrier();                        // enables b23-region stages
    asm volatile("" ::: "memory");

    // ---- ph4: read next-tile a0' (8); stage b23-region; MFMA Q4 = m1 x n23 (no wait) ----
    if (rd_next) {
#pragma unroll
      for (int i = 0; i < 4; i++) { A0[i][0] = LDA(nxt, i, 0); A0[i][1] = LDA(nxt, i, 1); }
    }
    if (pre2) { stB(nr + 2, 0, kp, cur); stB(nr + 2, 1, kp, cur); }
    __builtin_amdgcn_s_setprio(1);
#pragma unroll
    for (int i = 0; i < 4; i++)
#pragma unroll
      for (int j = 0; j < 2; j++) {
        acc[i + 4][j + 2] = __builtin_amdgcn_mfma_f32_16x16x32_bf16(A1[i][0], B23[j][0], acc[i + 4][j + 2], 0, 0, 0);
        acc[i + 4][j + 2] = __builtin_amdgcn_mfma_f32_16x16x32_bf16(A1[i][1], B23[j][1], acc[i + 4][j + 2], 0, 0, 0);
      }
    __builtin_amdgcn_s_setprio(0);
    // no tile-end barrier: next ph1 issues no stages; WAR for next ph2's stages
    // is covered by next ph1's lgkm(8) + its closing barrier.
  }

  // epilogue
#pragma unroll
  for (int i = 0; i < 8; i++)
#pragma unroll
    for (int j = 0; j < 4; j++)
#pragma unroll
      for (int r = 0; r < 4; r++) {
        int row = bm + wm * 128 + i * 16 + quad * 4 + r;
        int col = bn + wn * 64 + j * 16 + l16;
        float v = acc[i][j][r];
        if (OUTF32) ((float*)Cv)[(size_t)row * N + col] = v;
        else ((u16*)Cv)[(size_t)row * N + col] = f2bf(v);
      }
}

// ----- fused RMSNorm + RoPE, in place on bf16 [token][stride]; 1 wave/head -----
__global__ void rmsnorm_rope(u16* __restrict__ x, const float* __restrict__ w,
                             const float* __restrict__ fc, const float* __restrict__ fsn,
                             int nh, int stride, float outscale) {
  int token = blockIdx.x;
  int head = blockIdx.y * 4 + (threadIdx.x >> 6);
  if (head >= nh) return;
  int lane = threadIdx.x & 63;
  int s = token & (S_ - 1);
  u16* p = x + (size_t)token * stride + head * D_;
  float v0 = bf2f(p[lane]);
  float v1 = bf2f(p[lane + 64]);
  float v2 = bf2f(p[lane + 128]);
  float v3 = bf2f(p[lane + 192]);
  float ss = v0 * v0 + v1 * v1 + v2 * v2 + v3 * v3;
  for (int off = 32; off; off >>= 1) ss += __shfl_xor(ss, off, 64);
  float rs = rsqrtf(ss * (1.0f / D_) + EPS_);
  float n0 = v0 * rs * (1.0f + w[lane]);
  float n1 = v1 * rs * (1.0f + w[lane + 64]);
  float n2 = v2 * rs * (1.0f + w[lane + 128]);
  float n3 = v3 * rs * (1.0f + w[lane + 192]);
  float c0 = fc[s * 128 + lane], s0 = fsn[s * 128 + lane];
  float c1 = fc[s * 128 + lane + 64], s1 = fsn[s * 128 + lane + 64];
  p[lane]       = f2bf((n0 * c0 - n2 * s0) * outscale);
  p[lane + 128] = f2bf((n0 * s0 + n2 * c0) * outscale);
  p[lane + 64]  = f2bf((n1 * c1 - n3 * s1) * outscale);
  p[lane + 192] = f2bf((n1 * s1 + n3 * c1) * outscale);
}

// ---------------- flash attention, causal, GQA rep=2, D=256 ----------------
// v4 + merged-qkv strides: Q/K rows have stride 8192.
__global__ __launch_bounds__(256, 3) void flash_attn(const u16* __restrict__ Q,
                                                     const u16* __restrict__ Kb,
                                                     const u16* __restrict__ Vt,
                                                     u16* __restrict__ O) {
  __shared__ __align__(16) u16 Ks[2][8 * 1024];   // [buf][chunk c][key 0..31][slot-swz 32 d]
  __shared__ __align__(16) u16 Vs[8 * 1024];      // [d 0..255][slot-swz 32 k]
  int t = threadIdx.x, lane = t & 63, wave = t >> 6;
  int quad = lane >> 4, l16 = lane & 15;
  int h = blockIdx.y, b = blockIdx.z;
  int kvh = h >> 1;

  int swz = ((lane & 3) ^ ((lane >> 2) & 3)) * 8;        // staging-side d/k offset
  int rswz = (quad ^ (l16 & 3)) * 8;                     // read-side slot offset
  const u16* kst = Kb + (size_t)(b * S_ + (lane >> 2)) * QKS_ + kvh * D_ + wave * 64 + swz;
  const u16* vst = Vt + ((size_t)b << 22) + (size_t)(kvh * D_ + wave * 64 + (lane >> 2)) * S_ + swz;

  auto stageK = [&](int kt, int bufi) {
    u16* kdst = &Ks[bufi][wave * 2048];
    const u16* ksrc = kst + (size_t)(kt * 32) * QKS_;
#pragma unroll
    for (int c2 = 0; c2 < 2; c2++)
#pragma unroll
      for (int r = 0; r < 2; r++)
        gll16(ksrc + (size_t)(r * 16) * QKS_ + c2 * 32, kdst + c2 * 1024 + r * 512);
  };  // 4 gll16
  auto stageV = [&](int kt) {
    u16* vdst = &Vs[wave * 2048];
#pragma unroll
    for (int c = 0; c < 4; c++)
      gll16(vst + (size_t)(c * 16) * S_ + kt * 32, vdst + c * 512);
  };  // 4 gll16

#pragma unroll 1
  for (int half = 0; half < 2; half++) {
    // big q-tile first, then the paired small one: iters (64-2bx) + (2bx+2) = 66
    int qb = (half == 0) ? (31 - (int)blockIdx.x) * 64 : (int)blockIdx.x * 64;
    int qw = qb + wave * 16;

    bf16x8 qf[8];
    const u16* qp = Q + ((size_t)(b * S_) + qw + l16) * QKS_ + h * D_;
#pragma unroll
    for (int c = 0; c < 8; c++) qf[c] = *(const bf16x8*)(qp + c * 32 + quad * 8);

    f32x4 o_acc[16] = {};
    float m_s = -3e38f, l_s = 0.f;    // per-lane softmax state for row q = qw + l16

    int nkt = (qb + 64) >> 5;
    stageK(0, 0);
    stageV(0);
#pragma unroll 1
    for (int kt = 0; kt < nkt; kt++) {
      int cur = kt & 1;
      asm volatile("s_waitcnt vmcnt(4)" ::: "memory");
      __builtin_amdgcn_s_barrier();
      asm volatile("" ::: "memory");
      if (kt + 1 < nkt) stageK(kt + 1, cur ^ 1);

      // ---- QK (swapped): sc[key][q], q = l16 ----
      f32x4 sc0 = {}, sc1 = {};
#pragma unroll
      for (int c = 0; c < 8; c++) {
        bf16x8 k0 = *(const bf16x8*)(&Ks[cur][c * 1024 + l16 * 32 + rswz]);
        bf16x8 k1 = *(const bf16x8*)(&Ks[cur][c * 1024 + (l16 + 16) * 32 + rswz]);
        sc0 = __builtin_amdgcn_mfma_f32_16x16x32_bf16(k0, qf[c], sc0, 0, 0, 0);
        sc1 = __builtin_amdgcn_mfma_f32_16x16x32_bf16(k1, qf[c], sc1, 0, 0, 0);
      }

      // ---- lane-local online softmax (row q = qw + l16) ----
      int qg = qw + l16;
      int kbase = kt * 32 + quad * 4;
      float p0[4], p1[4];
      float mx = -1e30f;
#pragma unroll
      for (int r = 0; r < 4; r++) {
        p0[r] = (kbase + r <= qg) ? sc0[r] : -1e30f;
        p1[r] = (kbase + 16 + r <= qg) ? sc1[r] : -1e30f;
        mx = fmaxf(mx, fmaxf(p0[r], p1[r]));
      }
      mx = fmaxf(mx, __shfl_xor(mx, 16));
      mx = fmaxf(mx, __shfl_xor(mx, 32));
      float mn = fmaxf(m_s, mx);
      bool chg = mn > m_s;
      float rsum = 0.f;
#pragma unroll
      for (int r = 0; r < 4; r++) {
        p0[r] = __expf(p0[r] - mn);
        p1[r] = __expf(p1[r] - mn);
        rsum += p0[r] + p1[r];
      }
      if (__any((int)chg)) {
        float alpha = __expf(m_s - mn);
        float ar[4];
#pragma unroll
        for (int r = 0; r < 4; r++) ar[r] = __shfl(alpha, quad * 20 + r);
#pragma unroll
        for (int nt = 0; nt < 16; nt++)
#pragma unroll
          for (int r = 0; r < 4; r++) o_acc[nt][r] *= ar[r];
        l_s *= alpha;
      }
      m_s = mn;
      rsum += __shfl_xor(rsum, 16);
      rsum += __shfl_xor(rsum, 32);
      l_s += rsum;

      // ---- P: C-layout -> A-frag fully in-register (2-stage butterfly) ----
      unsigned int w_[4], x_[4], gl[4], gh[4], sn[4], rc[4];
      w_[0] = (unsigned)f2bf(p0[0]) | ((unsigned)f2bf(p0[1]) << 16);
      w_[1] = (unsigned)f2bf(p0[2]) | ((unsigned)f2bf(p0[3]) << 16);
      w_[2] = (unsigned)f2bf(p1[0]) | ((unsigned)f2bf(p1[1]) << 16);
      w_[3] = (unsigned)f2bf(p1[2]) | ((unsigned)f2bf(p1[3]) << 16);
#pragma unroll
      for (int i = 0; i < 4; i++) x_[i] = (unsigned)__shfl_xor((int)w_[i], 16);
      bool odd = (quad & 1) != 0;
      gl[0] = odd ? x_[0] : w_[0]; gl[1] = odd ? x_[1] : w_[1];
      gl[2] = odd ? w_[0] : x_[0]; gl[3] = odd ? w_[1] : x_[1];
      gh[0] = odd ? x_[2] : w_[2]; gh[1] = odd ? x_[3] : w_[3];
      gh[2] = odd ? w_[2] : x_[2]; gh[3] = odd ? w_[3] : x_[3];
#pragma unroll
      for (int i = 0; i < 4; i++) sn[i] = odd ? gl[i] : gh[i];
#pragma unroll
      for (int i = 0; i < 4; i++) rc[i] = (unsigned)__shfl_xor((int)sn[i], 32);
      union { unsigned int u[4]; bf16x8 v; } pfc;
#pragma unroll
      for (int i = 0; i < 4; i++)
        pfc.u[i] = (quad == 0) ? gl[i] : (quad == 3) ? gh[i] : rc[i];
      bf16x8 pf = pfc.v;

      if (kt + 1 < nkt) asm volatile("s_waitcnt vmcnt(4)" ::: "memory");
      else              asm volatile("s_waitcnt vmcnt(0)" ::: "memory");
      __builtin_amdgcn_s_barrier();
      asm volatile("" ::: "memory");

      // ---- PV ----
#pragma unroll
      for (int nt = 0; nt < 16; nt++) {
        bf16x8 vf = *(const bf16x8*)(&Vs[(nt * 16 + l16) * 32 + rswz]);
        o_acc[nt] = __builtin_amdgcn_mfma_f32_16x16x32_bf16(pf, vf, o_acc[nt], 0, 0, 0);
      }

      asm volatile("s_waitcnt lgkmcnt(0)" ::: "memory");
      __builtin_amdgcn_s_barrier();
      asm volatile("" ::: "memory");
      if (kt + 1 < nkt) stageV(kt + 1);
    }

    float invl = 1.0f / l_s;
    float inv_r[4];
#pragma unroll
    for (int r = 0; r < 4; r++) inv_r[r] = __shfl(invl, quad * 20 + r);
    for (int r = 0; r < 4; r++) {
      int qg2 = qw + quad * 4 + r;
      u16* op = O + ((size_t)(b * S_) + qg2) * HD_ + h * D_;
      for (int nt = 0; nt < 16; nt++) op[nt * 16 + l16] = f2bf(o_acc[nt][r] * inv_r[r]);
    }
  }
}

extern "C" void kernel_launch(void* const* d_in, const int* in_sizes, int n_in,
                              void* d_out, int out_size, void* d_ws, size_t ws_size,
                              hipStream_t stream) {
  const float* hs  = (const float*)d_in[0];
  const float* fc  = (const float*)d_in[1];
  const float* fsn = (const float*)d_in[2];
  // d_in[3] = mask: causal, replicated analytically
  const float* qw  = (const float*)d_in[4];
  const float* kw  = (const float*)d_in[5];
  const float* vw  = (const float*)d_in[6];
  const float* ow  = (const float*)d_in[7];
  const float* qnw = (const float*)d_in[8];
  const float* knw = (const float*)d_in[9];

  char* ws = (char*)d_ws;
  // layout (bytes):
  u16* x_bf   = (u16*)(ws + 0);          // 4096*3072*2 = 25165824 (dead after QKV GEMM)
  u16* vt     = (u16*)(ws + 0);          // 2*2048*2048*2 = 16777216 (overlays dead x_bf)
  u16* wqkv_t = (u16*)(ws + 25165824);   // [8192][3072] = 50331648 (q|k|v transposed, contiguous)
  u16* kw_t   = (u16*)(ws + 50331648);   // = wqkv_t + 4096 rows
  u16* vw_t   = (u16*)(ws + 62914560);   // = wqkv_t + 6144 rows
  u16* ow_t   = (u16*)(ws + 75497472);   // [3072][4096] = 25165824
  u16* xqkv   = (u16*)(ws + 100663296);  // [4096][8192] = 67108864 -> end 167772160
  u16* attn   = (u16*)(ws + 25165824);   // overlays dead wqkv_t after QKV GEMM (33.5MB <= 50.3MB)

  cast_f32_bf16<<<12288, 256, 0, stream>>>(hs, x_bf, 4096 * 3072 / 4);
  transpose_cast<<<dim3(64, 48), 256, 0, stream>>>(qw, wqkv_t, 3072, 4096);
  transpose_cast<<<dim3(32, 48), 256, 0, stream>>>(kw, kw_t, 3072, 2048);
  transpose_cast<<<dim3(32, 48), 256, 0, stream>>>(vw, vw_t, 3072, 2048);
  transpose_cast<<<dim3(48, 64), 256, 0, stream>>>(ow, ow_t, 4096, 3072);

  // merged QKV projection: [4096][3072] x [8192][3072]^T -> [4096][8192]
  gemm256<false><<<dim3(32, 16), 512, 0, stream>>>(x_bf, wqkv_t, xqkv, 4096, 8192, 3072);

  rmsnorm_rope<<<dim3(4096, 4), 256, 0, stream>>>(xqkv, qnw, fc, fsn, 16, QKS_, SCALE_);
  rmsnorm_rope<<<dim3(4096, 2), 256, 0, stream>>>(xqkv + 4096, knw, fc, fsn, 8, QKS_, 1.0f);

  transpose_v<<<dim3(32, 64), 256, 0, stream>>>(xqkv + 6144, vt);

  flash_attn<<<dim3(16, 16, 2), 256, 0, stream>>>(xqkv, xqkv + 4096, vt, attn);

  gemm256<true><<<dim3(12, 16), 512, 0, stream>>>(attn, ow_t, (float*)d_out, 4096, 3072, 4096);
}

// Round 7
// 747.066 us; speedup vs baseline: 1.0432x; 1.0147x over previous
//
#include <hip/hip_runtime.h>
#include <hip/hip_bf16.h>
#include <cstdint>

#define B_   2
#define S_   2048
#define HID_ 3072
#define H_   16
#define KV_  8
#define D_   256
#define HD_  4096   // H_*D_
#define KVD_ 2048   // KV_*D_
#define QKS_ 8192   // merged qkv row stride

constexpr float EPS_   = 1e-6f;
constexpr float SCALE_ = 0.0625f;   // 256^-0.5

typedef unsigned short u16;
typedef __attribute__((ext_vector_type(8))) short bf16x8;
typedef __attribute__((ext_vector_type(4))) float f32x4;

__device__ inline float bf2f(u16 u) { return __uint_as_float(((unsigned int)u) << 16); }
__device__ inline u16 f2bf(float f) {
  unsigned int x = __float_as_uint(f);
  x += 0x7fffu + ((x >> 16) & 1u);   // RNE
  return (u16)(x >> 16);
}

// async global->LDS, 16B per lane; lds base must be wave-uniform, data lands at base + lane*16
__device__ inline void gll16(const u16* g, u16* l) {
  __builtin_amdgcn_global_load_lds((const __attribute__((address_space(1))) unsigned int*)g,
                                   (__attribute__((address_space(3))) unsigned int*)l,
                                   16, 0, 0);
}

// ---------------- elementwise cast f32 -> bf16 (n4 = n/4) ----------------
__global__ void cast_f32_bf16(const float* __restrict__ in, u16* __restrict__ out, int n4) {
  int i = blockIdx.x * blockDim.x + threadIdx.x;
  if (i < n4) {
    float4 v = ((const float4*)in)[i];
    ushort4 o;
    o.x = f2bf(v.x); o.y = f2bf(v.y); o.z = f2bf(v.z); o.w = f2bf(v.w);
    ((ushort4*)out)[i] = o;
  }
}

// ------------- transpose+cast: in[K][N] f32 -> out[N][K] bf16 -------------
__global__ void transpose_cast(const float* __restrict__ in, u16* __restrict__ out, int K, int N) {
  __shared__ __align__(16) float tile[64][65];
  int n0 = blockIdx.x * 64, k0 = blockIdx.y * 64;
  int t = threadIdx.x;
  int rr = t >> 4, cc = (t & 15) * 4;
  for (int i = 0; i < 4; i++) {
    float4 v = *(const float4*)(&in[(size_t)(k0 + rr + 16 * i) * N + n0 + cc]);
    tile[rr + 16 * i][cc + 0] = v.x; tile[rr + 16 * i][cc + 1] = v.y;
    tile[rr + 16 * i][cc + 2] = v.z; tile[rr + 16 * i][cc + 3] = v.w;
  }
  __syncthreads();
  for (int i = 0; i < 4; i++) {
    int orow = rr + 16 * i;  // n index
    ushort4 o;
    o.x = f2bf(tile[cc + 0][orow]); o.y = f2bf(tile[cc + 1][orow]);
    o.z = f2bf(tile[cc + 2][orow]); o.w = f2bf(tile[cc + 3][orow]);
    *(ushort4*)(&out[(size_t)(n0 + orow) * K + k0 + cc]) = o;
  }
}

// ----- bf16 transpose: in (xqkv V cols, stride 8192) -> out[b][2048 n][2048 s] -----
__global__ void transpose_v(const u16* __restrict__ in, u16* __restrict__ out) {
  __shared__ __align__(16) u16 tile[64][68];
  int n0 = blockIdx.x * 64, tk0 = blockIdx.y * 64;
  int b = tk0 >> 11, s0 = tk0 & (S_ - 1);
  int t = threadIdx.x;
  int rr = t >> 4, cc = (t & 15) * 4;
  for (int i = 0; i < 4; i++) {
    ushort4 v = *(const ushort4*)(&in[(size_t)(tk0 + rr + 16 * i) * QKS_ + n0 + cc]);
    tile[rr + 16 * i][cc + 0] = v.x; tile[rr + 16 * i][cc + 1] = v.y;
    tile[rr + 16 * i][cc + 2] = v.z; tile[rr + 16 * i][cc + 3] = v.w;
  }
  __syncthreads();
  for (int i = 0; i < 4; i++) {
    int orow = rr + 16 * i;  // n index
    ushort4 o;
    o.x = tile[cc + 0][orow]; o.y = tile[cc + 1][orow];
    o.z = tile[cc + 2][orow]; o.w = tile[cc + 3][orow];
    *(ushort4*)(&out[((size_t)b << 22) + (size_t)(n0 + orow) * S_ + s0 + cc]) = o;
  }
}

// ===== 256x256 8-wave GEMM, 1-barrier-per-tile free-run: C = A * Bt^T =====
// v4 schedule: per tile, each wave free-runs {read A1; lgkm(8); Q1; read B23;
// lgkm(4); Q2; lgkm(0); vmcnt(0); BARRIER; stage t+2; Q3; read B01'(nxt);
// Q4; read A0'(nxt)} — reads always >=1 MFMA-cluster ahead (counted lgkm),
// next-tile R1 hidden under Q3/Q4, single convergence point per tile.
// Quadrant order makes operands die exactly when next-tile reads reuse their
// registers (no reg double-buffer). WAR: all cur reads drained (lgkm 0) and
// own stages drained (vmcnt 0, issued a tile earlier -> free) before the
// barrier; stages for t+2 (into buf cur) issued just after it.
template <bool OUTF32>
__global__ __launch_bounds__(512, 2) void gemm256(const u16* __restrict__ A,
                                                  const u16* __restrict__ Bt,
                                                  void* __restrict__ Cv, int M, int N, int K) {
  __shared__ __align__(16) u16 As[2][16384];
  __shared__ __align__(16) u16 Bs[2][16384];
  int t = threadIdx.x, lane = t & 63, wave = t >> 6;
  int quad = lane >> 4, l16 = lane & 15;
  int wm = wave >> 2, wn = wave & 3;

  // XCD-chunked bid swizzle (requires nwg % 8 == 0; 512 and 192 both qualify)
  int nwg = gridDim.x * gridDim.y;
  int bid = blockIdx.y * gridDim.x + blockIdx.x;
  int sbid = (bid & 7) * (nwg >> 3) + (bid >> 3);
  int bn = (sbid % gridDim.x) * 256;
  int bm = (sbid / gridDim.x) * 256;

  // staging: one gll16 fills one 16x32 subtile (1KB); lane l -> row l>>2,
  // phys slot l&3 holding logical slot (l&3)^((l>>3)&3)
  int srow = lane >> 2;
  int scol8 = ((lane & 3) ^ ((lane >> 3) & 3)) * 8;
  const u16* ap = A + (size_t)(bm + srow) * K + scol8;
  const u16* bp = Bt + (size_t)(bn + srow) * K + scol8;
  int nr = (wave & 1) + ((wave >> 1) << 2);   // B subtile row set per wave

  auto stA = [&](int sr, int sc, int k0, int bufi) {
    gll16(ap + (size_t)(sr * 16) * K + k0 + sc * 32, &As[bufi][(sr * 2 + sc) * 512]);
  };
  auto stB = [&](int sr, int sc, int k0, int bufi) {
    gll16(bp + (size_t)(sr * 16) * K + k0 + sc * 32, &Bs[bufi][(sr * 2 + sc) * 512]);
  };
  auto stageTile = [&](int kt, int bufi) {   // 8 gll16/wave, full A+B tile
    int k0 = kt * 64;
    stA(wave, 0, k0, bufi); stA(wave, 1, k0, bufi);
    stA(wave + 8, 0, k0, bufi); stA(wave + 8, 1, k0, bufi);
    stB(nr, 0, k0, bufi); stB(nr, 1, k0, bufi);
    stB(nr + 2, 0, k0, bufi); stB(nr + 2, 1, k0, bufi);
  };

  // frag read offset within a subtile (uniform banks: slot = quad ^ ((l16>>1)&3))
  int rsw = l16 * 32 + ((quad ^ ((l16 >> 1) & 3)) * 8);
  auto LDA = [&](int bufi, int i, int ks) {
    return *(const bf16x8*)(&As[bufi][((wm * 8 + i) * 2 + ks) * 512 + rsw]);
  };
  auto LDB = [&](int bufi, int j, int ks) {
    return *(const bf16x8*)(&Bs[bufi][((wn * 4 + j) * 2 + ks) * 512 + rsw]);
  };

  f32x4 acc[8][4] = {};
  int NT = K >> 6;

  // prologue: stage tiles 0,1; wait tile 0; pre-read R1(0) = B01 + A0
  stageTile(0, 0);
  stageTile(1, 1);
  asm volatile("s_waitcnt vmcnt(8)" ::: "memory");
  __builtin_amdgcn_s_barrier();
  asm volatile("" ::: "memory");

  bf16x8 A0[4][2], A1[4][2], B01[2][2], B23[2][2];
#pragma unroll
  for (int j = 0; j < 2; j++) { B01[j][0] = LDB(0, j, 0); B01[j][1] = LDB(0, j, 1); }
#pragma unroll
  for (int i = 0; i < 4; i++) { A0[i][0] = LDA(0, i, 0); A0[i][1] = LDA(0, i, 1); }

#pragma unroll 1
  for (int kt = 0; kt < NT; kt++) {
    int cur = kt & 1, nxt = cur ^ 1;

    // a: read A1 (8) [cur]
#pragma unroll
    for (int i = 0; i < 4; i++) { A1[i][0] = LDA(cur, i + 4, 0); A1[i][1] = LDA(cur, i + 4, 1); }
    // b: R1 done (A1 may fly); Q1 = A0 x B01
    asm volatile("s_waitcnt lgkmcnt(8)" ::: "memory");
#pragma unroll
    for (int i = 0; i < 4; i++)
#pragma unroll
      for (int j = 0; j < 2; j++) {
        acc[i][j] = __builtin_amdgcn_mfma_f32_16x16x32_bf16(A0[i][0], B01[j][0], acc[i][j], 0, 0, 0);
        acc[i][j] = __builtin_amdgcn_mfma_f32_16x16x32_bf16(A0[i][1], B01[j][1], acc[i][j], 0, 0, 0);
      }
    // c: read B23 (4) [cur]
#pragma unroll
    for (int j = 0; j < 2; j++) { B23[j][0] = LDB(cur, j + 2, 0); B23[j][1] = LDB(cur, j + 2, 1); }
    // d: A1 done (B23 may fly); Q2 = A1 x B01  (B01 dead after)
    asm volatile("s_waitcnt lgkmcnt(4)" ::: "memory");
#pragma unroll
    for (int i = 0; i < 4; i++)
#pragma unroll
      for (int j = 0; j < 2; j++) {
        acc[i + 4][j] = __builtin_amdgcn_mfma_f32_16x16x32_bf16(A1[i][0], B01[j][0], acc[i + 4][j], 0, 0, 0);
        acc[i + 4][j] = __builtin_amdgcn_mfma_f32_16x16x32_bf16(A1[i][1], B01[j][1], acc[i + 4][j], 0, 0, 0);
      }
    // e: drain all cur reads + own stages for tile t+1 (issued a tile ago)
    asm volatile("s_waitcnt lgkmcnt(0)" ::: "memory");
    asm volatile("s_waitcnt vmcnt(0)" ::: "memory");
    // f: single convergence point per tile
    __builtin_amdgcn_s_barrier();
    asm volatile("" ::: "memory");
    // g: stage tile t+2 into buf cur (WAR-safe: all cur reads drained pre-barrier)
    if (kt + 2 < NT) stageTile(kt + 2, cur);
    // i: Q3 = A0 x B23  (A0 dead after)
    __builtin_amdgcn_s_setprio(1);
#pragma unroll
    for (int i = 0; i < 4; i++)
#pragma unroll
      for (int j = 0; j < 2; j++) {
        acc[i][j + 2] = __builtin_amdgcn_mfma_f32_16x16x32_bf16(A0[i][0], B23[j][0], acc[i][j + 2], 0, 0, 0);
        acc[i][j + 2] = __builtin_amdgcn_mfma_f32_16x16x32_bf16(A0[i][1], B23[j][1], acc[i][j + 2], 0, 0, 0);
      }
    __builtin_amdgcn_s_setprio(0);
    // h1: read next-tile B01' (4) [nxt] (B01 regs dead)
    if (kt + 1 < NT) {
#pragma unroll
      for (int j = 0; j < 2; j++) { B01[j][0] = LDB(nxt, j, 0); B01[j][1] = LDB(nxt, j, 1); }
    }
    // j: Q4 = A1 x B23
    __builtin_amdgcn_s_setprio(1);
#pragma unroll
    for (int i = 0; i < 4; i++)
#pragma unroll
      for (int j = 0; j < 2; j++) {
        acc[i + 4][j + 2] = __builtin_amdgcn_mfma_f32_16x16x32_bf16(A1[i][0], B23[j][0], acc[i + 4][j + 2], 0, 0, 0);
        acc[i + 4][j + 2] = __builtin_amdgcn_mfma_f32_16x16x32_bf16(A1[i][1], B23[j][1], acc[i + 4][j + 2], 0, 0, 0);
      }
    __builtin_amdgcn_s_setprio(0);
    // h2: read next-tile A0' (8) [nxt] (A0 regs dead)
    if (kt + 1 < NT) {
#pragma unroll
      for (int i = 0; i < 4; i++) { A0[i][0] = LDA(nxt, i, 0); A0[i][1] = LDA(nxt, i, 1); }
    }
  }

  // epilogue
#pragma unroll
  for (int i = 0; i < 8; i++)
#pragma unroll
    for (int j = 0; j < 4; j++)
#pragma unroll
      for (int r = 0; r < 4; r++) {
        int row = bm + wm * 128 + i * 16 + quad * 4 + r;
        int col = bn + wn * 64 + j * 16 + l16;
        float v = acc[i][j][r];
        if (OUTF32) ((float*)Cv)[(size_t)row * N + col] = v;
        else ((u16*)Cv)[(size_t)row * N + col] = f2bf(v);
      }
}

// ----- fused RMSNorm + RoPE, in place on bf16 [token][stride]; 1 wave/head -----
__global__ void rmsnorm_rope(u16* __restrict__ x, const float* __restrict__ w,
                             const float* __restrict__ fc, const float* __restrict__ fsn,
                             int nh, int stride, float outscale) {
  int token = blockIdx.x;
  int head = blockIdx.y * 4 + (threadIdx.x >> 6);
  if (head >= nh) return;
  int lane = threadIdx.x & 63;
  int s = token & (S_ - 1);
  u16* p = x + (size_t)token * stride + head * D_;
  float v0 = bf2f(p[lane]);
  float v1 = bf2f(p[lane + 64]);
  float v2 = bf2f(p[lane + 128]);
  float v3 = bf2f(p[lane + 192]);
  float ss = v0 * v0 + v1 * v1 + v2 * v2 + v3 * v3;
  for (int off = 32; off; off >>= 1) ss += __shfl_xor(ss, off, 64);
  float rs = rsqrtf(ss * (1.0f / D_) + EPS_);
  float n0 = v0 * rs * (1.0f + w[lane]);
  float n1 = v1 * rs * (1.0f + w[lane + 64]);
  float n2 = v2 * rs * (1.0f + w[lane + 128]);
  float n3 = v3 * rs * (1.0f + w[lane + 192]);
  float c0 = fc[s * 128 + lane], s0 = fsn[s * 128 + lane];
  float c1 = fc[s * 128 + lane + 64], s1 = fsn[s * 128 + lane + 64];
  p[lane]       = f2bf((n0 * c0 - n2 * s0) * outscale);
  p[lane + 128] = f2bf((n0 * s0 + n2 * c0) * outscale);
  p[lane + 64]  = f2bf((n1 * c1 - n3 * s1) * outscale);
  p[lane + 192] = f2bf((n1 * s1 + n3 * c1) * outscale);
}

// ---------------- flash attention, causal, GQA rep=2, D=256 ----------------
// v4 + merged-qkv strides: Q/K rows have stride 8192.
__global__ __launch_bounds__(256, 3) void flash_attn(const u16* __restrict__ Q,
                                                     const u16* __restrict__ Kb,
                                                     const u16* __restrict__ Vt,
                                                     u16* __restrict__ O) {
  __shared__ __align__(16) u16 Ks[2][8 * 1024];   // [buf][chunk c][key 0..31][slot-swz 32 d]
  __shared__ __align__(16) u16 Vs[8 * 1024];      // [d 0..255][slot-swz 32 k]
  int t = threadIdx.x, lane = t & 63, wave = t >> 6;
  int quad = lane >> 4, l16 = lane & 15;
  int h = blockIdx.y, b = blockIdx.z;
  int kvh = h >> 1;

  int swz = ((lane & 3) ^ ((lane >> 2) & 3)) * 8;        // staging-side d/k offset
  int rswz = (quad ^ (l16 & 3)) * 8;                     // read-side slot offset
  const u16* kst = Kb + (size_t)(b * S_ + (lane >> 2)) * QKS_ + kvh * D_ + wave * 64 + swz;
  const u16* vst = Vt + ((size_t)b << 22) + (size_t)(kvh * D_ + wave * 64 + (lane >> 2)) * S_ + swz;

  auto stageK = [&](int kt, int bufi) {
    u16* kdst = &Ks[bufi][wave * 2048];
    const u16* ksrc = kst + (size_t)(kt * 32) * QKS_;
#pragma unroll
    for (int c2 = 0; c2 < 2; c2++)
#pragma unroll
      for (int r = 0; r < 2; r++)
        gll16(ksrc + (size_t)(r * 16) * QKS_ + c2 * 32, kdst + c2 * 1024 + r * 512);
  };  // 4 gll16
  auto stageV = [&](int kt) {
    u16* vdst = &Vs[wave * 2048];
#pragma unroll
    for (int c = 0; c < 4; c++)
      gll16(vst + (size_t)(c * 16) * S_ + kt * 32, vdst + c * 512);
  };  // 4 gll16

#pragma unroll 1
  for (int half = 0; half < 2; half++) {
    // big q-tile first, then the paired small one: iters (64-2bx) + (2bx+2) = 66
    int qb = (half == 0) ? (31 - (int)blockIdx.x) * 64 : (int)blockIdx.x * 64;
    int qw = qb + wave * 16;

    bf16x8 qf[8];
    const u16* qp = Q + ((size_t)(b * S_) + qw + l16) * QKS_ + h * D_;
#pragma unroll
    for (int c = 0; c < 8; c++) qf[c] = *(const bf16x8*)(qp + c * 32 + quad * 8);

    f32x4 o_acc[16] = {};
    float m_s = -3e38f, l_s = 0.f;    // per-lane softmax state for row q = qw + l16

    int nkt = (qb + 64) >> 5;
    stageK(0, 0);
    stageV(0);
#pragma unroll 1
    for (int kt = 0; kt < nkt; kt++) {
      int cur = kt & 1;
      asm volatile("s_waitcnt vmcnt(4)" ::: "memory");
      __builtin_amdgcn_s_barrier();
      asm volatile("" ::: "memory");
      if (kt + 1 < nkt) stageK(kt + 1, cur ^ 1);

      // ---- QK (swapped): sc[key][q], q = l16 ----
      f32x4 sc0 = {}, sc1 = {};
#pragma unroll
      for (int c = 0; c < 8; c++) {
        bf16x8 k0 = *(const bf16x8*)(&Ks[cur][c * 1024 + l16 * 32 + rswz]);
        bf16x8 k1 = *(const bf16x8*)(&Ks[cur][c * 1024 + (l16 + 16) * 32 + rswz]);
        sc0 = __builtin_amdgcn_mfma_f32_16x16x32_bf16(k0, qf[c], sc0, 0, 0, 0);
        sc1 = __builtin_amdgcn_mfma_f32_16x16x32_bf16(k1, qf[c], sc1, 0, 0, 0);
      }

      // ---- lane-local online softmax (row q = qw + l16) ----
      int qg = qw + l16;
      int kbase = kt * 32 + quad * 4;
      float p0[4], p1[4];
      float mx = -1e30f;
#pragma unroll
      for (int r = 0; r < 4; r++) {
        p0[r] = (kbase + r <= qg) ? sc0[r] : -1e30f;
        p1[r] = (kbase + 16 + r <= qg) ? sc1[r] : -1e30f;
        mx = fmaxf(mx, fmaxf(p0[r], p1[r]));
      }
      mx = fmaxf(mx, __shfl_xor(mx, 16));
      mx = fmaxf(mx, __shfl_xor(mx, 32));
      float mn = fmaxf(m_s, mx);
      bool chg = mn > m_s;
      float rsum = 0.f;
#pragma unroll
      for (int r = 0; r < 4; r++) {
        p0[r] = __expf(p0[r] - mn);
        p1[r] = __expf(p1[r] - mn);
        rsum += p0[r] + p1[r];
      }
      if (__any((int)chg)) {
        float alpha = __expf(m_s - mn);
        float ar[4];
#pragma unroll
        for (int r = 0; r < 4; r++) ar[r] = __shfl(alpha, quad * 20 + r);
#pragma unroll
        for (int nt = 0; nt < 16; nt++)
#pragma unroll
          for (int r = 0; r < 4; r++) o_acc[nt][r] *= ar[r];
        l_s *= alpha;
      }
      m_s = mn;
      rsum += __shfl_xor(rsum, 16);
      rsum += __shfl_xor(rsum, 32);
      l_s += rsum;

      // ---- P: C-layout -> A-frag fully in-register (2-stage butterfly) ----
      unsigned int w_[4], x_[4], gl[4], gh[4], sn[4], rc[4];
      w_[0] = (unsigned)f2bf(p0[0]) | ((unsigned)f2bf(p0[1]) << 16);
      w_[1] = (unsigned)f2bf(p0[2]) | ((unsigned)f2bf(p0[3]) << 16);
      w_[2] = (unsigned)f2bf(p1[0]) | ((unsigned)f2bf(p1[1]) << 16);
      w_[3] = (unsigned)f2bf(p1[2]) | ((unsigned)f2bf(p1[3]) << 16);
#pragma unroll
      for (int i = 0; i < 4; i++) x_[i] = (unsigned)__shfl_xor((int)w_[i], 16);
      bool odd = (quad & 1) != 0;
      gl[0] = odd ? x_[0] : w_[0]; gl[1] = odd ? x_[1] : w_[1];
      gl[2] = odd ? w_[0] : x_[0]; gl[3] = odd ? w_[1] : x_[1];
      gh[0] = odd ? x_[2] : w_[2]; gh[1] = odd ? x_[3] : w_[3];
      gh[2] = odd ? w_[2] : x_[2]; gh[3] = odd ? w_[3] : x_[3];
#pragma unroll
      for (int i = 0; i < 4; i++) sn[i] = odd ? gl[i] : gh[i];
#pragma unroll
      for (int i = 0; i < 4; i++) rc[i] = (unsigned)__shfl_xor((int)sn[i], 32);
      union { unsigned int u[4]; bf16x8 v; } pfc;
#pragma unroll
      for (int i = 0; i < 4; i++)
        pfc.u[i] = (quad == 0) ? gl[i] : (quad == 3) ? gh[i] : rc[i];
      bf16x8 pf = pfc.v;

      if (kt + 1 < nkt) asm volatile("s_waitcnt vmcnt(4)" ::: "memory");
      else              asm volatile("s_waitcnt vmcnt(0)" ::: "memory");
      __builtin_amdgcn_s_barrier();
      asm volatile("" ::: "memory");

      // ---- PV ----
#pragma unroll
      for (int nt = 0; nt < 16; nt++) {
        bf16x8 vf = *(const bf16x8*)(&Vs[(nt * 16 + l16) * 32 + rswz]);
        o_acc[nt] = __builtin_amdgcn_mfma_f32_16x16x32_bf16(pf, vf, o_acc[nt], 0, 0, 0);
      }

      asm volatile("s_waitcnt lgkmcnt(0)" ::: "memory");
      __builtin_amdgcn_s_barrier();
      asm volatile("" ::: "memory");
      if (kt + 1 < nkt) stageV(kt + 1);
    }

    float invl = 1.0f / l_s;
    float inv_r[4];
#pragma unroll
    for (int r = 0; r < 4; r++) inv_r[r] = __shfl(invl, quad * 20 + r);
    for (int r = 0; r < 4; r++) {
      int qg2 = qw + quad * 4 + r;
      u16* op = O + ((size_t)(b * S_) + qg2) * HD_ + h * D_;
      for (int nt = 0; nt < 16; nt++) op[nt * 16 + l16] = f2bf(o_acc[nt][r] * inv_r[r]);
    }
  }
}

extern "C" void kernel_launch(void* const* d_in, const int* in_sizes, int n_in,
                              void* d_out, int out_size, void* d_ws, size_t ws_size,
                              hipStream_t stream) {
  const float* hs  = (const float*)d_in[0];
  const float* fc  = (const float*)d_in[1];
  const float* fsn = (const float*)d_in[2];
  // d_in[3] = mask: causal, replicated analytically
  const float* qw  = (const float*)d_in[4];
  const float* kw  = (const float*)d_in[5];
  const float* vw  = (const float*)d_in[6];
  const float* ow  = (const float*)d_in[7];
  const float* qnw = (const float*)d_in[8];
  const float* knw = (const float*)d_in[9];

  char* ws = (char*)d_ws;
  // layout (bytes):
  u16* x_bf   = (u16*)(ws + 0);          // 4096*3072*2 = 25165824 (dead after QKV GEMM)
  u16* vt     = (u16*)(ws + 0);          // 2*2048*2048*2 = 16777216 (overlays dead x_bf)
  u16* wqkv_t = (u16*)(ws + 25165824);   // [8192][3072] = 50331648 (q|k|v transposed, contiguous)
  u16* kw_t   = (u16*)(ws + 50331648);   // = wqkv_t + 4096 rows
  u16* vw_t   = (u16*)(ws + 62914560);   // = wqkv_t + 6144 rows
  u16* ow_t   = (u16*)(ws + 75497472);   // [3072][4096] = 25165824
  u16* xqkv   = (u16*)(ws + 100663296);  // [4096][8192] = 67108864 -> end 167772160
  u16* attn   = (u16*)(ws + 25165824);   // overlays dead wqkv_t after QKV GEMM (33.5MB <= 50.3MB)

  cast_f32_bf16<<<12288, 256, 0, stream>>>(hs, x_bf, 4096 * 3072 / 4);
  transpose_cast<<<dim3(64, 48), 256, 0, stream>>>(qw, wqkv_t, 3072, 4096);
  transpose_cast<<<dim3(32, 48), 256, 0, stream>>>(kw, kw_t, 3072, 2048);
  transpose_cast<<<dim3(32, 48), 256, 0, stream>>>(vw, vw_t, 3072, 2048);
  transpose_cast<<<dim3(48, 64), 256, 0, stream>>>(ow, ow_t, 4096, 3072);

  // merged QKV projection: [4096][3072] x [8192][3072]^T -> [4096][8192]
  gemm256<false><<<dim3(32, 16), 512, 0, stream>>>(x_bf, wqkv_t, xqkv, 4096, 8192, 3072);

  rmsnorm_rope<<<dim3(4096, 4), 256, 0, stream>>>(xqkv, qnw, fc, fsn, 16, QKS_, SCALE_);
  rmsnorm_rope<<<dim3(4096, 2), 256, 0, stream>>>(xqkv + 4096, knw, fc, fsn, 8, QKS_, 1.0f);

  transpose_v<<<dim3(32, 64), 256, 0, stream>>>(xqkv + 6144, vt);

  flash_attn<<<dim3(16, 16, 2), 256, 0, stream>>>(xqkv, xqkv + 4096, vt, attn);

  gemm256<true><<<dim3(12, 16), 512, 0, stream>>>(attn, ow_t, (float*)d_out, 4096, 3072, 4096);
}